// Round 14
// baseline (1149.016 us; speedup 1.0000x reference)
//
#include <hip/hip_runtime.h>
#include <cstdint>
#include <cstddef>

#define BB 256
#define TT 2048
#define VV 128
#define HH 64

typedef __attribute__((ext_vector_type(8))) short short8;
typedef __attribute__((ext_vector_type(4))) float f32x4;
typedef __attribute__((ext_vector_type(2))) float f32x2;

__device__ __forceinline__ float frcp(float x){ return __builtin_amdgcn_rcpf(x); }
__device__ __forceinline__ float sigm(float x){ return frcp(1.f + __expf(-x)); }
__device__ __forceinline__ float tanh_f(float x){ return 1.f - 2.f*frcp(1.f + __expf(2.f*x)); }

__device__ __forceinline__ void bar_lds(){
  asm volatile("s_waitcnt lgkmcnt(0)" ::: "memory");
  __builtin_amdgcn_s_barrier();
  __builtin_amdgcn_sched_barrier(0);
}

__device__ __forceinline__ void gload16(const void* g, void* l){
  __builtin_amdgcn_global_load_lds(
      (const __attribute__((address_space(1))) void*)g,
      (__attribute__((address_space(3))) void*)l, 16, 0, 0);
}

__device__ __forceinline__ unsigned short bf16hi(float x){
  unsigned u = __float_as_uint(x);
  return (unsigned short)((u + 0x7fffu + ((u>>16)&1u)) >> 16);
}
__device__ __forceinline__ void splitpack(const float* v8, short8& hi, short8& lo){
  #pragma unroll
  for (int j=0;j<8;++j){
    unsigned short h = bf16hi(v8[j]);
    float fh = __uint_as_float(((unsigned)h)<<16);
    unsigned short lw = bf16hi(v8[j] - fh);
    hi[j] = (short)h; lo[j] = (short)lw;
  }
}

__device__ __forceinline__ float qsum(float v){
  int t1 = __builtin_amdgcn_update_dpp(0, __float_as_int(v), 0xB1, 0xF, 0xF, true);
  v += __int_as_float(t1);
  int t2 = __builtin_amdgcn_update_dpp(0, __float_as_int(v), 0x4E, 0xF, 0xF, true);
  v += __int_as_float(t2);
  return v;
}

template<int CTRL>
__device__ __forceinline__ float dppmov(float v){
  return __int_as_float(__builtin_amdgcn_update_dpp(0, __float_as_int(v), CTRL, 0xF, 0xF, true));
}

__device__ __forceinline__ void pkfma(f32x2& acc, f32x2 a, f32x2 b){
  asm volatile("v_pk_fma_f32 %0, %1, %2, %0" : "+v"(acc) : "v"(a), "v"(b));
}

// ====================== kernel A0: weight conversion ======================
__global__ __launch_bounds__(256) void conv_w_k(
  const float* __restrict__ Wf, const float* __restrict__ Wi,
  const float* __restrict__ Wc, const float* __restrict__ Wo,
  const float* __restrict__ Wout,
  unsigned short* __restrict__ W4h, unsigned short* __restrict__ W4l,
  unsigned short* __restrict__ WOh, unsigned short* __restrict__ WOl)
{
  const int idx = blockIdx.x*256 + threadIdx.x;
  if (idx < 32768){
    const int j = idx&7, l=(idx>>3)&63, kk=(idx>>9)&3, nt=idx>>11;
    const int k = kk*32 + (l>>4)*8 + j;
    const int n = nt*16 + (l&15);
    const int g = n&3, colw = n>>2;
    const float* Ws = (g==0)?Wf:((g==1)?Wi:((g==2)?Wc:Wo));
    const float v = Ws[k*HH + colw];
    const unsigned short h = bf16hi(v);
    const float fh = __uint_as_float(((unsigned)h)<<16);
    W4h[idx] = h; W4l[idx] = bf16hi(v - fh);
  }
  if (idx < 8192){
    const int j = idx&7, l=(idx>>3)&63, kk=(idx>>9)&1, jt=idx>>10;
    const int k = kk*32 + (l>>4)*8 + j;
    const int jc = jt*16 + (l&15);
    const float v = Wout[k*VV + jc];
    const unsigned short h = bf16hi(v);
    const float fh = __uint_as_float(((unsigned)h)<<16);
    WOh[idx] = h; WOl[idx] = bf16hi(v - fh);
  }
}

// ====================== kernel A: PRE = x @ W4 (bf16 3-pass) ======================
__global__ __launch_bounds__(512,1) void pre_gemm_k(
  const float* __restrict__ x, const unsigned short* __restrict__ W4h,
  const unsigned short* __restrict__ W4l, float* __restrict__ PRE)
{
  __shared__ __align__(16) unsigned short XFh[16384];
  __shared__ __align__(16) unsigned short XFl[16384];
  const int tid = threadIdx.x, wv = tid>>6, l = tid&63, b = blockIdx.x;

  short8 Bh[2][4], Bl[2][4];
  #pragma unroll
  for (int ntl=0; ntl<2; ++ntl){
    const int nt = wv*2 + ntl;
    #pragma unroll
    for (int kk=0; kk<4; ++kk){
      Bh[ntl][kk] = *(const short8*)(W4h + ((nt*4+kk)*64 + l)*8);
      Bl[ntl][kk] = *(const short8*)(W4l + ((nt*4+kk)*64 + l)*8);
    }
  }

  #pragma unroll 1
  for (int mt=0; mt<16; ++mt){
    const size_t base_row = (size_t)b*TT + mt*128;
    #pragma unroll
    for (int i=0;i<4;++i){
      const int G = tid*4+i;
      const int lf = G&63, kk=(G>>6)&3, m8=G>>8;
      const float* src = x + (base_row + m8*16 + (lf&15))*VV + kk*32 + (lf>>4)*8;
      const f32x4 u = *(const f32x4*)src;
      const f32x4 v = *(const f32x4*)(src+4);
      float tmp[8] = {u[0],u[1],u[2],u[3], v[0],v[1],v[2],v[3]};
      short8 hi, lo; splitpack(tmp, hi, lo);
      *(short8*)&XFh[(size_t)G*8] = hi;
      *(short8*)&XFl[(size_t)G*8] = lo;
    }
    bar_lds();
    for (int m8=0; m8<8; ++m8){
      short8 Ah[4], Al[4];
      #pragma unroll
      for (int kk=0;kk<4;++kk){
        Ah[kk] = *(const short8*)&XFh[((m8*4+kk)*64 + l)*8];
        Al[kk] = *(const short8*)&XFl[((m8*4+kk)*64 + l)*8];
      }
      #pragma unroll
      for (int ntl=0; ntl<2; ++ntl){
        f32x4 acc = {0.f,0.f,0.f,0.f};
        #pragma unroll
        for (int kk=0;kk<4;++kk){
          acc = __builtin_amdgcn_mfma_f32_16x16x32_bf16(Al[kk], Bh[ntl][kk], acc, 0,0,0);
          acc = __builtin_amdgcn_mfma_f32_16x16x32_bf16(Ah[kk], Bl[ntl][kk], acc, 0,0,0);
          acc = __builtin_amdgcn_mfma_f32_16x16x32_bf16(Ah[kk], Bh[ntl][kk], acc, 0,0,0);
        }
        const int nt = wv*2 + ntl;
        float* dst = PRE + (base_row + m8*16 + (l>>4)*4)*256 + nt*16 + (l&15);
        #pragma unroll
        for (int r=0;r<4;++r) dst[(size_t)r*256] = acc[r];
      }
    }
    bar_lds();
  }
}

// ====================== kernel B: 4-wave recurrence, TWO rows per block ======================
// Same per-row structure as proven recur8 (716us). The ~500cy/step of pure
// latency stall is filled by interleaving a SECOND independent batch row:
// shared weights, two h-rings, two PRE FIFOs, two c's, one barrier covers
// both. pkfma chains round-robin across all 8 chains (4 gates x 2 rows) so
// in-order asm issue never dependency-stalls.
__global__ __launch_bounds__(256,1) void recur9_k(
  const float* __restrict__ W_f, const float* __restrict__ b_f,
  const float* __restrict__ W_if, const float* __restrict__ b_if,
  const float* __restrict__ W_ic, const float* __restrict__ b_ic,
  const float* __restrict__ W_o,  const float* __restrict__ b_o,
  const float* __restrict__ PRE,  float* __restrict__ H)
{
  __shared__ __align__(16) float hring[2*32*HH];   // two h rings (16KB)
  const int tid=threadIdx.x, wv=tid>>6, l=tid&63, b=blockIdx.x;
  const int col = wv*16 + (l>>2), q = l&3;
  const bool qb0 = (l&1)!=0, qb1 = (l&2)!=0;

  f32x2 wf2[8], wi2[8], wc2[8], wo2[8];
  #pragma unroll
  for (int m=0;m<8;++m){
    const size_t k0 = (size_t)(VV + q*16 + 2*m)*HH + col;
    wf2[m] = f32x2{W_f [k0], W_f [k0+HH]};
    wi2[m] = f32x2{W_if[k0], W_if[k0+HH]};
    wc2[m] = f32x2{W_ic[k0], W_ic[k0+HH]};
    wo2[m] = f32x2{W_o [k0], W_o [k0+HH]};
  }
  const float bq  = ((q==0)?b_f:(q==1)?b_if:(q==2)?b_ic:b_o)[col];
  const float sgn = (q==2)? 2.f : -1.f;
  const float aA  = (q==2)? -2.f : 1.f;
  const float aB  = (q==2)? 1.f : 0.f;

  const int rA = 2*b, rB = 2*b+1;
  const float* PRElA = PRE + (size_t)rA*TT*256 + wv*64 + l;
  const float* PRElB = PRE + (size_t)rB*TT*256 + wv*64 + l;
  float* HbA = H + (size_t)rA*TT*HH;
  float* HbB = H + (size_t)rB*TT*HH;
  const f32x4* hring4 = (const f32x4*)hring;

  if (tid < HH){ hring[31*HH + tid] = 0.f; hring[2048 + 31*HH + tid] = 0.f; }

  float pfA[8], pfB[8];
  #pragma unroll
  for (int j=0;j<8;++j){ pfA[j] = PRElA[(size_t)j*256]; pfB[j] = PRElB[(size_t)j*256]; }

  bar_lds();

  float cA = 0.f, cB = 0.f;
  int hoff = 31*16 + q*4;     // f32x4 index (row A); row B = +512
  int woff = col;             // float index (row A); row B = +2048

  #pragma unroll 1
  for (int t8=0; t8<TT; t8+=8){
    #pragma unroll
    for (int j=0;j<8;++j){
      const int t = t8+j;
      // off-chain: burst-store finalized h rows (wave1 -> A, wave2 -> B)
      if (t>0 && (t&15)==0){
        if (wv==1){
          #pragma unroll
          for (int i=0;i<4;++i){
            const int rt = t-16 + i*4 + (l>>4);
            const f32x4 v = hring4[(rt&31)*16 + (l&15)];
            *(f32x4*)(HbA + (size_t)rt*HH + (l&15)*4) = v;
          }
        } else if (wv==2){
          #pragma unroll
          for (int i=0;i<4;++i){
            const int rt = t-16 + i*4 + (l>>4);
            const f32x4 v = hring4[512 + (rt&31)*16 + (l&15)];
            *(f32x4*)(HbB + (size_t)rt*HH + (l&15)*4) = v;
          }
        }
      }
      // h reads for both rows (offsets precomputed last step)
      const f32x4 hA0 = hring4[hoff+0], hA1 = hring4[hoff+1];
      const f32x4 hA2 = hring4[hoff+2], hA3 = hring4[hoff+3];
      const f32x4 hB0 = hring4[512+hoff+0], hB1 = hring4[512+hoff+1];
      const f32x4 hB2 = hring4[512+hoff+2], hB3 = hring4[512+hoff+3];
      // prefetch PRE rows t+8 (independent)
      const float nxtA = PRElA[(size_t)((t+8)&(TT-1))*256];
      const float nxtB = PRElB[(size_t)((t+8)&(TT-1))*256];
      const float pqA = pfA[j], pqB = pfB[j];

      const f32x2 pA[8] = { {hA0[0],hA0[1]},{hA0[2],hA0[3]},{hA1[0],hA1[1]},{hA1[2],hA1[3]},
                            {hA2[0],hA2[1]},{hA2[2],hA2[3]},{hA3[0],hA3[1]},{hA3[2],hA3[3]} };
      const f32x2 pB[8] = { {hB0[0],hB0[1]},{hB0[2],hB0[3]},{hB1[0],hB1[1]},{hB1[2],hB1[3]},
                            {hB2[0],hB2[1]},{hB2[2],hB2[3]},{hB3[0],hB3[1]},{hB3[2],hB3[3]} };
      f32x2 a0A={0,0},a1A={0,0},a2A={0,0},a3A={0,0};
      f32x2 a0B={0,0},a1B={0,0},a2B={0,0},a3B={0,0};
      // round-robin across 8 independent chains: in-order issue never stalls
      #pragma unroll
      for (int m=0;m<8;++m){
        pkfma(a0A,pA[m],wf2[m]); pkfma(a1A,pA[m],wi2[m]);
        pkfma(a2A,pA[m],wc2[m]); pkfma(a3A,pA[m],wo2[m]);
        pkfma(a0B,pB[m],wf2[m]); pkfma(a1B,pB[m],wi2[m]);
        pkfma(a2B,pB[m],wc2[m]); pkfma(a3B,pB[m],wo2[m]);
      }
      const float a0sA=a0A[0]+a0A[1], a1sA=a1A[0]+a1A[1], a2sA=a2A[0]+a2A[1], a3sA=a3A[0]+a3A[1];
      const float a0sB=a0B[0]+a0B[1], a1sB=a1B[0]+a1B[1], a2sB=a2B[0]+a2B[1], a3sB=a3B[0]+a3B[1];
      // select-transpose quad reduce (both rows; independent dpp chains)
      float tAA = qb0 ? a1sA : a0sA;  float tBA = qb0 ? a0sA : a1sA;
      float tAB = qb0 ? a1sB : a0sB;  float tBB = qb0 ? a0sB : a1sB;
      tAA += dppmov<0xB1>(tBA);       tAB += dppmov<0xB1>(tBB);
      float tCA = qb0 ? a3sA : a2sA;  float tDA = qb0 ? a2sA : a3sA;
      float tCB = qb0 ? a3sB : a2sB;  float tDB = qb0 ? a2sB : a3sB;
      tCA += dppmov<0xB1>(tDA);       tCB += dppmov<0xB1>(tDB);
      float rA_ = qb1 ? tCA : tAA;    float rrA = qb1 ? tAA : tCA;
      float rB_ = qb1 ? tCB : tAB;    float rrB = qb1 ? tAB : tCB;
      rA_ += dppmov<0x4E>(rrA);       rB_ += dppmov<0x4E>(rrB);
      // unified single-gate activation (2 trans each, interleaved)
      const float xxA = rA_ + pqA + bq;
      const float xxB = rB_ + pqB + bq;
      const float eA = __expf(sgn*xxA);
      const float eB = __expf(sgn*xxB);
      const float actA = fmaf(aA, frcp(1.f+eA), aB);
      const float actB = fmaf(aA, frcp(1.f+eB), aB);
      // quad broadcasts
      const float fA_ = dppmov<0x00>(actA), afA = dppmov<0x55>(actA);
      const float adA = dppmov<0xAA>(actA), oA_ = dppmov<0xFF>(actA);
      const float fB_ = dppmov<0x00>(actB), afB = dppmov<0x55>(actB);
      const float adB = dppmov<0xAA>(actB), oB_ = dppmov<0xFF>(actB);
      cA = cA*fA_ + adA*afA;
      cB = cB*fB_ + adB*afB;
      const float hvA = tanh_f(cA) * oA_;
      const float hvB = tanh_f(cB) * oB_;
      if (q==0){ hring[woff] = hvA; hring[2048+woff] = hvB; }
      pfA[j] = nxtA; pfB[j] = nxtB;
      hoff = (hoff + 16) & 511;
      woff = (woff + 64) & 2047;
      bar_lds();
    }
  }
  // final bursts: rows TT-16..TT-1
  if (wv==1){
    #pragma unroll
    for (int i=0;i<4;++i){
      const int rt = TT-16 + i*4 + (l>>4);
      const f32x4 v = hring4[(rt&31)*16 + (l&15)];
      *(f32x4*)(HbA + (size_t)rt*HH + (l&15)*4) = v;
    }
  } else if (wv==2){
    #pragma unroll
    for (int i=0;i<4;++i){
      const int rt = TT-16 + i*4 + (l>>4);
      const f32x4 v = hring4[512 + (rt&31)*16 + (l&15)];
      *(f32x4*)(HbB + (size_t)rt*HH + (l&15)*4) = v;
    }
  }
}

// ====================== kernel C: out = softmax(H@W_out + b_out) ======================
__global__ __launch_bounds__(512,1) void logit_k(
  const float* __restrict__ H, const unsigned short* __restrict__ WOh,
  const unsigned short* __restrict__ WOl, const float* __restrict__ b_out,
  float* __restrict__ out)
{
  const int tid=threadIdx.x, wv=tid>>6, l=tid&63, b=blockIdx.x;
  short8 Bh[8][2], Bl[8][2];
  #pragma unroll
  for (int jt=0;jt<8;++jt){
    #pragma unroll
    for (int kk=0;kk<2;++kk){
      Bh[jt][kk] = *(const short8*)(WOh + ((jt*2+kk)*64 + l)*8);
      Bl[jt][kk] = *(const short8*)(WOl + ((jt*2+kk)*64 + l)*8);
    }
  }
  float bj[8];
  #pragma unroll
  for (int jt=0;jt<8;++jt) bj[jt] = b_out[jt*16 + (l&15)];

  #pragma unroll 1
  for (int mt=0; mt<16; ++mt){
    const size_t row0 = (size_t)b*TT + mt*128 + wv*16;
    const float* hbase = H + (row0 + (l&15))*HH;
    short8 Ah[2], Al[2];
    #pragma unroll
    for (int kk=0;kk<2;++kk){
      const float* s = hbase + kk*32 + (l>>4)*8;
      const f32x4 u = *(const f32x4*)s;
      const f32x4 v = *(const f32x4*)(s+4);
      float tmp[8] = {u[0],u[1],u[2],u[3], v[0],v[1],v[2],v[3]};
      splitpack(tmp, Ah[kk], Al[kk]);
    }
    f32x4 acc[8];
    #pragma unroll
    for (int jt=0;jt<8;++jt){
      f32x4 a = {0.f,0.f,0.f,0.f};
      #pragma unroll
      for (int kk=0;kk<2;++kk){
        a = __builtin_amdgcn_mfma_f32_16x16x32_bf16(Al[kk], Bh[jt][kk], a, 0,0,0);
        a = __builtin_amdgcn_mfma_f32_16x16x32_bf16(Ah[kk], Bl[jt][kk], a, 0,0,0);
        a = __builtin_amdgcn_mfma_f32_16x16x32_bf16(Ah[kk], Bh[jt][kk], a, 0,0,0);
      }
      acc[jt] = a;
    }
    #pragma unroll
    for (int r=0;r<4;++r){
      float z[8];
      #pragma unroll
      for (int jt=0;jt<8;++jt) z[jt] = acc[jt][r] + bj[jt];
      float mx = z[0];
      #pragma unroll
      for (int jt=1;jt<8;++jt) mx = fmaxf(mx, z[jt]);
      mx = fmaxf(mx, __shfl_xor(mx,1));
      mx = fmaxf(mx, __shfl_xor(mx,2));
      mx = fmaxf(mx, __shfl_xor(mx,4));
      mx = fmaxf(mx, __shfl_xor(mx,8));
      float sum = 0.f;
      #pragma unroll
      for (int jt=0;jt<8;++jt){ z[jt] = __expf(z[jt]-mx); sum += z[jt]; }
      sum += __shfl_xor(sum,1);
      sum += __shfl_xor(sum,2);
      sum += __shfl_xor(sum,4);
      sum += __shfl_xor(sum,8);
      const float rs = frcp(sum);
      float* op = out + (row0 + (l>>4)*4 + r)*VV + (l&15);
      #pragma unroll
      for (int jt=0;jt<8;++jt) op[jt*16] = z[jt]*rs;
    }
  }
}

// ====================== fallback (R4 fused path, proven) ======================
#define XA_IDX(buf,kk,q,s) ((buf)*2048 + (((kk)*4+(q))*16+(s))*8)
#define HA_IDX(buf,kk,q,s) ((buf)*1024 + (((kk)*4+(q))*16+(s))*8)
#define NBF 128

__device__ __forceinline__ void gload16f(const float* g, float* l){
  __builtin_amdgcn_global_load_lds(
      (const __attribute__((address_space(1))) void*)g,
      (__attribute__((address_space(3))) void*)l, 16, 0, 0);
}

__global__ __launch_bounds__(512, 1) void fused_fb_k(
  const float* __restrict__ x,
  const float* __restrict__ W_f,  const float* __restrict__ b_f,
  const float* __restrict__ W_if, const float* __restrict__ b_if,
  const float* __restrict__ W_ic, const float* __restrict__ b_ic,
  const float* __restrict__ W_o,  const float* __restrict__ b_o,
  const float* __restrict__ W_out,const float* __restrict__ b_out,
  float* __restrict__ out)
{
  __shared__ __align__(16) float XR[4*16*VV];
  __shared__ __align__(16) short XAh[2*2048];
  __shared__ __align__(16) short XAl[2*2048];
  __shared__ __align__(16) float PRE[32*256];
  __shared__ __align__(16) short HAh[2*1024];
  __shared__ __align__(16) short HAl[2*1024];
  __shared__ __align__(16) float HR[32*HH];

  const int tid = threadIdx.x;
  const int wv  = tid >> 6;
  const int l   = tid & 63;
  const int row = blockIdx.x;
  const float* xrow = x   + (size_t)row*TT*VV;
  float*       orow = out + (size_t)row*TT*VV;

  if (wv < 4) {
    const int col = (wv&3)*16 + (l>>2);
    const int q   = l&3;
    float wh0[16], wh1[16], wh2[16], wh3[16];
    #pragma unroll
    for (int m=0;m<16;++m){
      const size_t kidx = (size_t)(VV + q*16 + m)*HH + col;
      wh0[m]=W_f[kidx]; wh1[m]=W_if[kidx]; wh2[m]=W_ic[kidx]; wh3[m]=W_o[kidx];
    }
    const float b0=b_f[col], b1=b_if[col], b2=b_ic[col], b3=b_o[col];
    if (tid < HH) HR[31*HH + tid] = 0.f;
    bar_lds(); bar_lds(); bar_lds();
    float c = 0.f;
    #pragma unroll 1
    for (int t=0; t<TT; ++t){
      const f32x4* hp = (const f32x4*)&HR[((t+31)&31)*HH + q*16];
      const f32x4 pre4 = *(const f32x4*)&PRE[(t&31)*256 + col*4];
      float d0=0.f,d1=0.f,d2=0.f,d3=0.f;
      #pragma unroll
      for (int m=0;m<4;++m){
        const f32x4 hv = hp[m];
        #pragma unroll
        for (int e=0;e<4;++e){
          const float s = hv[e];
          d0 = fmaf(s, wh0[m*4+e], d0);
          d1 = fmaf(s, wh1[m*4+e], d1);
          d2 = fmaf(s, wh2[m*4+e], d2);
          d3 = fmaf(s, wh3[m*4+e], d3);
        }
      }
      d0 = qsum(d0); d1 = qsum(d1); d2 = qsum(d2); d3 = qsum(d3);
      const float f  = sigm(d0 + pre4[0] + b0);
      const float fi = sigm(d1 + pre4[1] + b1);
      const float ci = tanh_f(d2 + pre4[2] + b2);
      const float o  = sigm(d3 + pre4[3] + b3);
      c = c*f + ci*fi;
      const float hv2 = tanh_f(c) * o;
      if (q==0) HR[(t&31)*HH + col] = hv2;
      bar_lds();
    }
    bar_lds();
  } else {
    const int pv = wv - 4;
    const int pt = pv*64 + l;
    short8 Bh[4][4], Bl[4][4];
    #pragma unroll
    for (int ntl=0; ntl<4; ++ntl){
      const int n = (pv*4+ntl)*16 + (l&15);
      const int g = n&3, colw = n>>2;
      const float* Ws = (g==0)?W_f:((g==1)?W_if:((g==2)?W_ic:W_o));
      #pragma unroll
      for (int kk=0;kk<4;++kk){
        float tmp[8];
        #pragma unroll
        for (int j=0;j<8;++j) tmp[j] = Ws[(size_t)(kk*32+(l>>4)*8+j)*HH + colw];
        splitpack(tmp, Bh[ntl][kk], Bl[ntl][kk]);
      }
    }
    short8 Lh[2][2], Ll[2][2];
    #pragma unroll
    for (int jt=0; jt<2; ++jt){
      const int j = (pv*2+jt)*16 + (l&15);
      #pragma unroll
      for (int kk=0;kk<2;++kk){
        float tmp[8];
        #pragma unroll
        for (int jj=0;jj<8;++jj) tmp[jj] = W_out[(size_t)(kk*32+(l>>4)*8+jj)*VV + j];
        splitpack(tmp, Lh[jt][kk], Ll[jt][kk]);
      }
    }
    auto GLOAD = [&](int bb){
      #pragma unroll
      for (int i=0;i<2;++i){
        const float* src = xrow + (size_t)bb*16*VV + pv*512 + i*256 + l*4;
        float* dst = &XR[(bb&3)*2048 + pv*512 + i*256];
        gload16f(src, dst);
      }
    };
    auto CONV = [&](int bb){
      if (pt < 256){
        const int buf=bb&1, kk=pt>>6, qq=(pt>>4)&3, s=pt&15;
        const float* src = &XR[(bb&3)*2048 + s*VV + kk*32 + qq*8];
        float tmp[8];
        #pragma unroll
        for (int j=0;j<8;++j) tmp[j] = src[j];
        short8 hi, lo; splitpack(tmp, hi, lo);
        *(short8*)&XAh[XA_IDX(buf,kk,qq,s)] = hi;
        *(short8*)&XAl[XA_IDX(buf,kk,qq,s)] = lo;
      }
    };
    auto PREB = [&](int bb){
      const int buf = bb&1;
      short8 Ah[4], Al[4];
      #pragma unroll
      for (int kk=0;kk<4;++kk){
        Ah[kk] = *(const short8*)&XAh[XA_IDX(buf,kk,(l>>4),(l&15))];
        Al[kk] = *(const short8*)&XAl[XA_IDX(buf,kk,(l>>4),(l&15))];
      }
      #pragma unroll
      for (int ntl=0; ntl<4; ++ntl){
        f32x4 acc = {0.f,0.f,0.f,0.f};
        #pragma unroll
        for (int kk=0;kk<4;++kk){
          acc = __builtin_amdgcn_mfma_f32_16x16x32_bf16(Al[kk], Bh[ntl][kk], acc, 0,0,0);
          acc = __builtin_amdgcn_mfma_f32_16x16x32_bf16(Ah[kk], Bl[ntl][kk], acc, 0,0,0);
          acc = __builtin_amdgcn_mfma_f32_16x16x32_bf16(Ah[kk], Bh[ntl][kk], acc, 0,0,0);
        }
        const int n  = (pv*4+ntl)*16 + (l&15);
        const int s0 = buf*16 + (l>>4)*4;
        #pragma unroll
        for (int r=0;r<4;++r) PRE[(s0+r)*256 + n] = acc[r];
      }
    };
    auto LOGB = [&](int bb){
      const int buf = bb&1;
      short8 Ah[2], Al[2];
      #pragma unroll
      for (int kk=0;kk<2;++kk){
        Ah[kk] = *(const short8*)&HAh[HA_IDX(buf,kk,(l>>4),(l&15))];
        Al[kk] = *(const short8*)&HAl[HA_IDX(buf,kk,(l>>4),(l&15))];
      }
      #pragma unroll
      for (int jt=0; jt<2; ++jt){
        f32x4 acc = {0.f,0.f,0.f,0.f};
        #pragma unroll
        for (int kk=0;kk<2;++kk){
          acc = __builtin_amdgcn_mfma_f32_16x16x32_bf16(Al[kk], Lh[jt][kk], acc, 0,0,0);
          acc = __builtin_amdgcn_mfma_f32_16x16x32_bf16(Ah[kk], Ll[jt][kk], acc, 0,0,0);
          acc = __builtin_amdgcn_mfma_f32_16x16x32_bf16(Ah[kk], Lh[jt][kk], acc, 0,0,0);
        }
        const int j  = (pv*2+jt)*16 + (l&15);
        const int t0 = bb*16 + (l>>4)*4;
        #pragma unroll
        for (int r=0;r<4;++r) orow[(size_t)(t0+r)*VV + j] = acc[r];
      }
    };
    auto RELAY = [&](int hs2){
      if (pt < 8){
        const int kk = pt>>2, qq = pt&3;
        const int buf = (hs2>>4)&1, s = hs2&15;
        const float* src = &HR[(hs2&31)*HH + kk*32 + qq*8];
        float tmp[8];
        #pragma unroll
        for (int j=0;j<8;++j) tmp[j] = src[j];
        short8 hi, lo; splitpack(tmp, hi, lo);
        *(short8*)&HAh[HA_IDX(buf,kk,qq,s)] = hi;
        *(short8*)&HAl[HA_IDX(buf,kk,qq,s)] = lo;
      }
    };
    GLOAD(0); GLOAD(1); GLOAD(2);
    asm volatile("s_waitcnt vmcnt(2)" ::: "memory");
    bar_lds();
    CONV(0); CONV(1);
    bar_lds();
    PREB(0);
    bar_lds();
    #pragma unroll 1
    for (int t=0; t<TT; ++t){
      if (t >= 1) RELAY(t-1);
      const int slot = t&15, blk = t>>4;
      if (slot==0){ if (blk+1 < NBF) PREB(blk+1); }
      else if (slot==1){ if (blk >= 1) LOGB(blk-1); }
      else if (slot==2){ if (blk+3 < NBF) GLOAD(blk+3); }
      else if (slot==3){ if (blk+2 < NBF) asm volatile("s_waitcnt vmcnt(2)" ::: "memory"); }
      else if (slot==4){ if (blk+2 < NBF) CONV(blk+2); }
      bar_lds();
    }
    RELAY(TT-1);
    bar_lds();
    LOGB(NBF-1);
  }
}

__global__ __launch_bounds__(256) void softmax_fb_k(float* __restrict__ out)
{
  const int r = blockIdx.x*4 + (threadIdx.x>>6);
  const int l = threadIdx.x & 63;
  float2* p = (float2*)(out + (size_t)r*VV);
  float2 v = p[l];
  float m = fmaxf(v.x, v.y);
  #pragma unroll
  for (int d=1; d<64; d<<=1) m = fmaxf(m, __shfl_xor(m, d));
  float e0 = __expf(v.x - m), e1 = __expf(v.y - m);
  float s = e0 + e1;
  #pragma unroll
  for (int d=1; d<64; d<<=1) s += __shfl_xor(s, d);
  float rs = frcp(s);
  p[l] = make_float2(e0*rs, e1*rs);
}

// ====================== host ======================
extern "C" void kernel_launch(void* const* d_in, const int* in_sizes, int n_in,
                              void* d_out, int out_size, void* d_ws, size_t ws_size,
                              hipStream_t stream) {
  const float* x     = (const float*)d_in[0];
  const float* W_f   = (const float*)d_in[1];
  const float* b_f   = (const float*)d_in[2];
  const float* W_if  = (const float*)d_in[3];
  const float* b_if  = (const float*)d_in[4];
  const float* W_ic  = (const float*)d_in[5];
  const float* b_ic  = (const float*)d_in[6];
  const float* W_o   = (const float*)d_in[7];
  const float* b_o   = (const float*)d_in[8];
  const float* W_out = (const float*)d_in[9];
  const float* b_out = (const float*)d_in[10];
  float* out = (float*)d_out;

  const size_t PRE_B = (size_t)BB*TT*256*sizeof(float);  // 512 MB
  const size_t H_B   = (size_t)BB*TT*HH*sizeof(float);   // 128 MB
  const size_t need  = PRE_B + H_B + 2*32768*2 + 2*8192*2;

  if (ws_size >= need) {
    char* w = (char*)d_ws;
    float* PRE  = (float*)w;
    float* Hbuf = (float*)(w + PRE_B);
    unsigned short* W4h = (unsigned short*)(w + PRE_B + H_B);
    unsigned short* W4l = W4h + 32768;
    unsigned short* WOh = W4l + 32768;
    unsigned short* WOl = WOh + 8192;
    hipLaunchKernelGGL(conv_w_k, dim3(128), dim3(256), 0, stream,
                       W_f, W_if, W_ic, W_o, W_out, W4h, W4l, WOh, WOl);
    hipLaunchKernelGGL(pre_gemm_k, dim3(BB), dim3(512), 0, stream, x, W4h, W4l, PRE);
    hipLaunchKernelGGL(recur9_k, dim3(BB/2), dim3(256), 0, stream,
                       W_f, b_f, W_if, b_if, W_ic, b_ic, W_o, b_o, PRE, Hbuf);
    hipLaunchKernelGGL(logit_k, dim3(BB), dim3(512), 0, stream, Hbuf, WOh, WOl, b_out, out);
  } else {
    hipLaunchKernelGGL(fused_fb_k, dim3(BB), dim3(512), 0, stream,
                       x, W_f, b_f, W_if, b_if, W_ic, b_ic, W_o, b_o,
                       W_out, b_out, out);
    hipLaunchKernelGGL(softmax_fb_k, dim3(BB*TT/4), dim3(256), 0, stream, out);
  }
}

// Round 15
// 864.251 us; speedup vs baseline: 1.3295x; 1.3295x over previous
//
#include <hip/hip_runtime.h>
#include <cstdint>
#include <cstddef>

#define BB 256
#define TT 2048
#define VV 128
#define HH 64

typedef __attribute__((ext_vector_type(8))) short short8;
typedef __attribute__((ext_vector_type(4))) float f32x4;
typedef __attribute__((ext_vector_type(2))) float f32x2;

__device__ __forceinline__ float frcp(float x){ return __builtin_amdgcn_rcpf(x); }
__device__ __forceinline__ float sigm(float x){ return frcp(1.f + __expf(-x)); }
__device__ __forceinline__ float tanh_f(float x){ return 1.f - 2.f*frcp(1.f + __expf(2.f*x)); }

__device__ __forceinline__ void bar_lds(){
  asm volatile("s_waitcnt lgkmcnt(0)" ::: "memory");
  __builtin_amdgcn_s_barrier();
  __builtin_amdgcn_sched_barrier(0);
}

__device__ __forceinline__ unsigned short bf16hi(float x){
  unsigned u = __float_as_uint(x);
  return (unsigned short)((u + 0x7fffu + ((u>>16)&1u)) >> 16);
}
__device__ __forceinline__ void splitpack(const float* v8, short8& hi, short8& lo){
  #pragma unroll
  for (int j=0;j<8;++j){
    unsigned short h = bf16hi(v8[j]);
    float fh = __uint_as_float(((unsigned)h)<<16);
    unsigned short lw = bf16hi(v8[j] - fh);
    hi[j] = (short)h; lo[j] = (short)lw;
  }
}

template<int CTRL>
__device__ __forceinline__ float dppmov(float v){
  return __int_as_float(__builtin_amdgcn_update_dpp(0, __float_as_int(v), CTRL, 0xF, 0xF, true));
}

__device__ __forceinline__ void pkfma(f32x2& acc, f32x2 a, f32x2 b){
  asm volatile("v_pk_fma_f32 %0, %1, %2, %0" : "+v"(acc) : "v"(a), "v"(b));
}

// ====================== kernel A0: weight conversion ======================
__global__ __launch_bounds__(256) void conv_w_k(
  const float* __restrict__ Wf, const float* __restrict__ Wi,
  const float* __restrict__ Wc, const float* __restrict__ Wo,
  const float* __restrict__ Wout,
  unsigned short* __restrict__ W4h, unsigned short* __restrict__ W4l,
  unsigned short* __restrict__ WOh, unsigned short* __restrict__ WOl)
{
  const int idx = blockIdx.x*256 + threadIdx.x;
  if (idx < 32768){
    const int j = idx&7, l=(idx>>3)&63, kk=(idx>>9)&3, nt=idx>>11;
    const int k = kk*32 + (l>>4)*8 + j;
    const int n = nt*16 + (l&15);
    const int g = n&3, colw = n>>2;
    const float* Ws = (g==0)?Wf:((g==1)?Wi:((g==2)?Wc:Wo));
    const float v = Ws[k*HH + colw];
    const unsigned short h = bf16hi(v);
    const float fh = __uint_as_float(((unsigned)h)<<16);
    W4h[idx] = h; W4l[idx] = bf16hi(v - fh);
  }
  if (idx < 8192){
    const int j = idx&7, l=(idx>>3)&63, kk=(idx>>9)&1, jt=idx>>10;
    const int k = kk*32 + (l>>4)*8 + j;
    const int jc = jt*16 + (l&15);
    const float v = Wout[k*VV + jc];
    const unsigned short h = bf16hi(v);
    const float fh = __uint_as_float(((unsigned)h)<<16);
    WOh[idx] = h; WOl[idx] = bf16hi(v - fh);
  }
}

// ====================== kernel A: PRE = x @ W4 (bf16 3-pass) ======================
__global__ __launch_bounds__(512,1) void pre_gemm_k(
  const float* __restrict__ x, const unsigned short* __restrict__ W4h,
  const unsigned short* __restrict__ W4l, float* __restrict__ PRE)
{
  __shared__ __align__(16) unsigned short XFh[16384];
  __shared__ __align__(16) unsigned short XFl[16384];
  const int tid = threadIdx.x, wv = tid>>6, l = tid&63, b = blockIdx.x;

  short8 Bh[2][4], Bl[2][4];
  #pragma unroll
  for (int ntl=0; ntl<2; ++ntl){
    const int nt = wv*2 + ntl;
    #pragma unroll
    for (int kk=0; kk<4; ++kk){
      Bh[ntl][kk] = *(const short8*)(W4h + ((nt*4+kk)*64 + l)*8);
      Bl[ntl][kk] = *(const short8*)(W4l + ((nt*4+kk)*64 + l)*8);
    }
  }

  #pragma unroll 1
  for (int mt=0; mt<16; ++mt){
    const size_t base_row = (size_t)b*TT + mt*128;
    #pragma unroll
    for (int i=0;i<4;++i){
      const int G = tid*4+i;
      const int lf = G&63, kk=(G>>6)&3, m8=G>>8;
      const float* src = x + (base_row + m8*16 + (lf&15))*VV + kk*32 + (lf>>4)*8;
      const f32x4 u = *(const f32x4*)src;
      const f32x4 v = *(const f32x4*)(src+4);
      float tmp[8] = {u[0],u[1],u[2],u[3], v[0],v[1],v[2],v[3]};
      short8 hi, lo; splitpack(tmp, hi, lo);
      *(short8*)&XFh[(size_t)G*8] = hi;
      *(short8*)&XFl[(size_t)G*8] = lo;
    }
    bar_lds();
    for (int m8=0; m8<8; ++m8){
      short8 Ah[4], Al[4];
      #pragma unroll
      for (int kk=0;kk<4;++kk){
        Ah[kk] = *(const short8*)&XFh[((m8*4+kk)*64 + l)*8];
        Al[kk] = *(const short8*)&XFl[((m8*4+kk)*64 + l)*8];
      }
      #pragma unroll
      for (int ntl=0; ntl<2; ++ntl){
        f32x4 acc = {0.f,0.f,0.f,0.f};
        #pragma unroll
        for (int kk=0;kk<4;++kk){
          acc = __builtin_amdgcn_mfma_f32_16x16x32_bf16(Al[kk], Bh[ntl][kk], acc, 0,0,0);
          acc = __builtin_amdgcn_mfma_f32_16x16x32_bf16(Ah[kk], Bl[ntl][kk], acc, 0,0,0);
          acc = __builtin_amdgcn_mfma_f32_16x16x32_bf16(Ah[kk], Bh[ntl][kk], acc, 0,0,0);
        }
        const int nt = wv*2 + ntl;
        float* dst = PRE + (base_row + m8*16 + (l>>4)*4)*256 + nt*16 + (l&15);
        #pragma unroll
        for (int r=0;r<4;++r) dst[(size_t)r*256] = acc[r];
      }
    }
    bar_lds();
  }
}

// ====================== kernel B: 4-wave recurrence (recur8 + chain trims) ======================
// recur8 (proven 716us) with: (1) h-burst moved after the pkfma issue so its
// LDS reads hide under reduce/act instead of delaying the chain-critical
// h-reads; (2) burst duty rotates waves 1->2->3; (3) pre+bias folded into the
// lane's own gate partial BEFORE the reduce (off-chain), so post-reduce chain
// is xx = r directly.
__global__ __launch_bounds__(256,1) void recur10_k(
  const float* __restrict__ W_f, const float* __restrict__ b_f,
  const float* __restrict__ W_if, const float* __restrict__ b_if,
  const float* __restrict__ W_ic, const float* __restrict__ b_ic,
  const float* __restrict__ W_o,  const float* __restrict__ b_o,
  const float* __restrict__ PRE,  float* __restrict__ H)
{
  __shared__ __align__(16) float hring[32*HH];   // h history ring (8KB)
  const int tid=threadIdx.x, wv=tid>>6, l=tid&63, b=blockIdx.x;
  const int col = wv*16 + (l>>2), q = l&3;
  const bool qb0 = (l&1)!=0, qb1 = (l&2)!=0;

  f32x2 wf2[8], wi2[8], wc2[8], wo2[8];
  #pragma unroll
  for (int m=0;m<8;++m){
    const size_t k0 = (size_t)(VV + q*16 + 2*m)*HH + col;
    wf2[m] = f32x2{W_f [k0], W_f [k0+HH]};
    wi2[m] = f32x2{W_if[k0], W_if[k0+HH]};
    wc2[m] = f32x2{W_ic[k0], W_ic[k0+HH]};
    wo2[m] = f32x2{W_o [k0], W_o [k0+HH]};
  }
  const float bq  = ((q==0)?b_f:(q==1)?b_if:(q==2)?b_ic:b_o)[col];
  const float sgn = (q==2)? 2.f : -1.f;
  const float aA  = (q==2)? -2.f : 1.f;
  const float aB  = (q==2)? 1.f : 0.f;
  // per-lane gate-select masks for folding pre+bias into the pre-reduce partial
  const float m0 = (q==0)?1.f:0.f, m1 = (q==1)?1.f:0.f;
  const float m2 = (q==2)?1.f:0.f, m3 = (q==3)?1.f:0.f;

  // per-lane PRE column: PRE[b][t][wv*64 + l]  (wave-coalesced 256B rows)
  const float* PREl = PRE + (size_t)b*TT*256 + wv*64 + l;
  float* Hb = H + (size_t)b*TT*HH;
  const f32x4* hring4 = (const f32x4*)hring;

  if (tid < HH) hring[31*HH + tid] = 0.f;   // h_{-1} = 0

  float pf[8];
  #pragma unroll
  for (int j=0;j<8;++j) pf[j] = PREl[(size_t)j*256];

  bar_lds();

  float c_ = 0.f;
  int hoff = 31*16 + q*4;     // f32x4 index of h quarter for step 0
  int woff = col;             // float index of h write for step 0

  #pragma unroll 1
  for (int t8=0; t8<TT; t8+=8){
    #pragma unroll
    for (int j=0;j<8;++j){
      const int t = t8+j;
      // chain-critical h reads FIRST after the barrier
      const f32x4 h0 = hring4[hoff+0], h1 = hring4[hoff+1];
      const f32x4 h2 = hring4[hoff+2], h3 = hring4[hoff+3];
      const float nxt = PREl[(size_t)((t+8)&(TT-1))*256];
      const float pqb = pf[j] + bq;        // off-chain (ready early)
      f32x2 a0={0.f,0.f}, a1={0.f,0.f}, a2={0.f,0.f}, a3={0.f,0.f};
      {
        const f32x2 p0 = f32x2{h0[0],h0[1]}, p1 = f32x2{h0[2],h0[3]};
        const f32x2 p2 = f32x2{h1[0],h1[1]}, p3 = f32x2{h1[2],h1[3]};
        const f32x2 p4 = f32x2{h2[0],h2[1]}, p5 = f32x2{h2[2],h2[3]};
        const f32x2 p6 = f32x2{h3[0],h3[1]}, p7 = f32x2{h3[2],h3[3]};
        pkfma(a0,p0,wf2[0]); pkfma(a1,p0,wi2[0]); pkfma(a2,p0,wc2[0]); pkfma(a3,p0,wo2[0]);
        pkfma(a0,p1,wf2[1]); pkfma(a1,p1,wi2[1]); pkfma(a2,p1,wc2[1]); pkfma(a3,p1,wo2[1]);
        pkfma(a0,p2,wf2[2]); pkfma(a1,p2,wi2[2]); pkfma(a2,p2,wc2[2]); pkfma(a3,p2,wo2[2]);
        pkfma(a0,p3,wf2[3]); pkfma(a1,p3,wi2[3]); pkfma(a2,p3,wc2[3]); pkfma(a3,p3,wo2[3]);
        pkfma(a0,p4,wf2[4]); pkfma(a1,p4,wi2[4]); pkfma(a2,p4,wc2[4]); pkfma(a3,p4,wo2[4]);
        pkfma(a0,p5,wf2[5]); pkfma(a1,p5,wi2[5]); pkfma(a2,p5,wc2[5]); pkfma(a3,p5,wo2[5]);
        pkfma(a0,p6,wf2[6]); pkfma(a1,p6,wi2[6]); pkfma(a2,p6,wc2[6]); pkfma(a3,p6,wo2[6]);
        pkfma(a0,p7,wf2[7]); pkfma(a1,p7,wi2[7]); pkfma(a2,p7,wc2[7]); pkfma(a3,p7,wo2[7]);
      }
      // off-chain: burst-store finalized h rows t-16..t-1 (rotating wave duty);
      // slots are stable for 16 steps, so placement here is safe.
      if (t>0 && (t&15)==0 && wv == 1 + ((t>>4)%3)){
        #pragma unroll
        for (int i=0;i<4;++i){
          const int rt = t-16 + i*4 + (l>>4);
          const f32x4 v = hring4[(rt&31)*16 + (l&15)];
          *(f32x4*)(Hb + (size_t)rt*HH + (l&15)*4) = v;
        }
      }
      // fold pre+bias into this lane's own gate partial (counted once in reduce)
      float a0s = fmaf(m0, pqb, a0[0]+a0[1]);
      float a1s = fmaf(m1, pqb, a1[0]+a1[1]);
      float a2s = fmaf(m2, pqb, a2[0]+a2[1]);
      float a3s = fmaf(m3, pqb, a3[0]+a3[1]);
      // select-transpose quad reduce: lane q ends with FULL sum of gate q
      float tA = qb0 ? a1s : a0s;
      float tB = qb0 ? a0s : a1s;
      tA += dppmov<0xB1>(tB);
      float tC = qb0 ? a3s : a2s;
      float tD = qb0 ? a2s : a3s;
      tC += dppmov<0xB1>(tD);
      float r  = qb1 ? tC : tA;
      float rr = qb1 ? tA : tC;
      r += dppmov<0x4E>(rr);
      // unified single-gate activation (2 trans slots); pre+bias already in r
      const float e   = __expf(sgn*r);
      const float rc  = frcp(1.f + e);
      const float act = fmaf(aA, rc, aB);
      // broadcast gate values within quad
      const float f_  = dppmov<0x00>(act);
      const float af  = dppmov<0x55>(act);
      const float ad  = dppmov<0xAA>(act);
      const float o_  = dppmov<0xFF>(act);
      c_ = c_*f_ + ad*af;
      const float hv = tanh_f(c_) * o_;
      if (q==0) hring[woff] = hv;
      pf[j] = nxt;
      hoff = (hoff + 16) & 511;
      woff = (woff + 64) & 2047;
      bar_lds();
    }
  }
  if (wv==1){  // final burst: rows TT-16..TT-1
    #pragma unroll
    for (int i=0;i<4;++i){
      const int rt = TT-16 + i*4 + (l>>4);
      const f32x4 v = hring4[(rt&31)*16 + (l&15)];
      *(f32x4*)(Hb + (size_t)rt*HH + (l&15)*4) = v;
    }
  }
}

// ====================== kernel C: out = softmax(H@W_out + b_out) ======================
__global__ __launch_bounds__(512,1) void logit_k(
  const float* __restrict__ H, const unsigned short* __restrict__ WOh,
  const unsigned short* __restrict__ WOl, const float* __restrict__ b_out,
  float* __restrict__ out)
{
  const int tid=threadIdx.x, wv=tid>>6, l=tid&63, b=blockIdx.x;
  short8 Bh[8][2], Bl[8][2];
  #pragma unroll
  for (int jt=0;jt<8;++jt){
    #pragma unroll
    for (int kk=0;kk<2;++kk){
      Bh[jt][kk] = *(const short8*)(WOh + ((jt*2+kk)*64 + l)*8);
      Bl[jt][kk] = *(const short8*)(WOl + ((jt*2+kk)*64 + l)*8);
    }
  }
  float bj[8];
  #pragma unroll
  for (int jt=0;jt<8;++jt) bj[jt] = b_out[jt*16 + (l&15)];

  #pragma unroll 1
  for (int mt=0; mt<16; ++mt){
    const size_t row0 = (size_t)b*TT + mt*128 + wv*16;
    const float* hbase = H + (row0 + (l&15))*HH;
    short8 Ah[2], Al[2];
    #pragma unroll
    for (int kk=0;kk<2;++kk){
      const float* s = hbase + kk*32 + (l>>4)*8;
      const f32x4 u = *(const f32x4*)s;
      const f32x4 v = *(const f32x4*)(s+4);
      float tmp[8] = {u[0],u[1],u[2],u[3], v[0],v[1],v[2],v[3]};
      splitpack(tmp, Ah[kk], Al[kk]);
    }
    f32x4 acc[8];
    #pragma unroll
    for (int jt=0;jt<8;++jt){
      f32x4 a = {0.f,0.f,0.f,0.f};
      #pragma unroll
      for (int kk=0;kk<2;++kk){
        a = __builtin_amdgcn_mfma_f32_16x16x32_bf16(Al[kk], Bh[jt][kk], a, 0,0,0);
        a = __builtin_amdgcn_mfma_f32_16x16x32_bf16(Ah[kk], Bl[jt][kk], a, 0,0,0);
        a = __builtin_amdgcn_mfma_f32_16x16x32_bf16(Ah[kk], Bh[jt][kk], a, 0,0,0);
      }
      acc[jt] = a;
    }
    #pragma unroll
    for (int r=0;r<4;++r){
      float z[8];
      #pragma unroll
      for (int jt=0;jt<8;++jt) z[jt] = acc[jt][r] + bj[jt];
      float mx = z[0];
      #pragma unroll
      for (int jt=1;jt<8;++jt) mx = fmaxf(mx, z[jt]);
      mx = fmaxf(mx, __shfl_xor(mx,1));
      mx = fmaxf(mx, __shfl_xor(mx,2));
      mx = fmaxf(mx, __shfl_xor(mx,4));
      mx = fmaxf(mx, __shfl_xor(mx,8));
      float sum = 0.f;
      #pragma unroll
      for (int jt=0;jt<8;++jt){ z[jt] = __expf(z[jt]-mx); sum += z[jt]; }
      sum += __shfl_xor(sum,1);
      sum += __shfl_xor(sum,2);
      sum += __shfl_xor(sum,4);
      sum += __shfl_xor(sum,8);
      const float rs = frcp(sum);
      float* op = out + (row0 + (l>>4)*4 + r)*VV + (l&15);
      #pragma unroll
      for (int jt=0;jt<8;++jt) op[jt*16] = z[jt]*rs;
    }
  }
}

// ====================== fallback (R4 fused path, proven) ======================
#define XA_IDX(buf,kk,q,s) ((buf)*2048 + (((kk)*4+(q))*16+(s))*8)
#define HA_IDX(buf,kk,q,s) ((buf)*1024 + (((kk)*4+(q))*16+(s))*8)
#define NBF 128

__device__ __forceinline__ float qsum_fb(float v){
  int t1 = __builtin_amdgcn_update_dpp(0, __float_as_int(v), 0xB1, 0xF, 0xF, true);
  v += __int_as_float(t1);
  int t2 = __builtin_amdgcn_update_dpp(0, __float_as_int(v), 0x4E, 0xF, 0xF, true);
  v += __int_as_float(t2);
  return v;
}

__device__ __forceinline__ void gload16f(const float* g, float* l){
  __builtin_amdgcn_global_load_lds(
      (const __attribute__((address_space(1))) void*)g,
      (__attribute__((address_space(3))) void*)l, 16, 0, 0);
}

__global__ __launch_bounds__(512, 1) void fused_fb_k(
  const float* __restrict__ x,
  const float* __restrict__ W_f,  const float* __restrict__ b_f,
  const float* __restrict__ W_if, const float* __restrict__ b_if,
  const float* __restrict__ W_ic, const float* __restrict__ b_ic,
  const float* __restrict__ W_o,  const float* __restrict__ b_o,
  const float* __restrict__ W_out,const float* __restrict__ b_out,
  float* __restrict__ out)
{
  __shared__ __align__(16) float XR[4*16*VV];
  __shared__ __align__(16) short XAh[2*2048];
  __shared__ __align__(16) short XAl[2*2048];
  __shared__ __align__(16) float PRE[32*256];
  __shared__ __align__(16) short HAh[2*1024];
  __shared__ __align__(16) short HAl[2*1024];
  __shared__ __align__(16) float HR[32*HH];

  const int tid = threadIdx.x;
  const int wv  = tid >> 6;
  const int l   = tid & 63;
  const int row = blockIdx.x;
  const float* xrow = x   + (size_t)row*TT*VV;
  float*       orow = out + (size_t)row*TT*VV;

  if (wv < 4) {
    const int col = (wv&3)*16 + (l>>2);
    const int q   = l&3;
    float wh0[16], wh1[16], wh2[16], wh3[16];
    #pragma unroll
    for (int m=0;m<16;++m){
      const size_t kidx = (size_t)(VV + q*16 + m)*HH + col;
      wh0[m]=W_f[kidx]; wh1[m]=W_if[kidx]; wh2[m]=W_ic[kidx]; wh3[m]=W_o[kidx];
    }
    const float b0=b_f[col], b1=b_if[col], b2=b_ic[col], b3=b_o[col];
    if (tid < HH) HR[31*HH + tid] = 0.f;
    bar_lds(); bar_lds(); bar_lds();
    float c = 0.f;
    #pragma unroll 1
    for (int t=0; t<TT; ++t){
      const f32x4* hp = (const f32x4*)&HR[((t+31)&31)*HH + q*16];
      const f32x4 pre4 = *(const f32x4*)&PRE[(t&31)*256 + col*4];
      float d0=0.f,d1=0.f,d2=0.f,d3=0.f;
      #pragma unroll
      for (int m=0;m<4;++m){
        const f32x4 hv = hp[m];
        #pragma unroll
        for (int e=0;e<4;++e){
          const float s = hv[e];
          d0 = fmaf(s, wh0[m*4+e], d0);
          d1 = fmaf(s, wh1[m*4+e], d1);
          d2 = fmaf(s, wh2[m*4+e], d2);
          d3 = fmaf(s, wh3[m*4+e], d3);
        }
      }
      d0 = qsum_fb(d0); d1 = qsum_fb(d1); d2 = qsum_fb(d2); d3 = qsum_fb(d3);
      const float f  = sigm(d0 + pre4[0] + b0);
      const float fi = sigm(d1 + pre4[1] + b1);
      const float ci = tanh_f(d2 + pre4[2] + b2);
      const float o  = sigm(d3 + pre4[3] + b3);
      c = c*f + ci*fi;
      const float hv2 = tanh_f(c) * o;
      if (q==0) HR[(t&31)*HH + col] = hv2;
      bar_lds();
    }
    bar_lds();
  } else {
    const int pv = wv - 4;
    const int pt = pv*64 + l;
    short8 Bh[4][4], Bl[4][4];
    #pragma unroll
    for (int ntl=0; ntl<4; ++ntl){
      const int n = (pv*4+ntl)*16 + (l&15);
      const int g = n&3, colw = n>>2;
      const float* Ws = (g==0)?W_f:((g==1)?W_if:((g==2)?W_ic:W_o));
      #pragma unroll
      for (int kk=0;kk<4;++kk){
        float tmp[8];
        #pragma unroll
        for (int j=0;j<8;++j) tmp[j] = Ws[(size_t)(kk*32+(l>>4)*8+j)*HH + colw];
        splitpack(tmp, Bh[ntl][kk], Bl[ntl][kk]);
      }
    }
    short8 Lh[2][2], Ll[2][2];
    #pragma unroll
    for (int jt=0; jt<2; ++jt){
      const int j = (pv*2+jt)*16 + (l&15);
      #pragma unroll
      for (int kk=0;kk<2;++kk){
        float tmp[8];
        #pragma unroll
        for (int jj=0;jj<8;++jj) tmp[jj] = W_out[(size_t)(kk*32+(l>>4)*8+jj)*VV + j];
        splitpack(tmp, Lh[jt][kk], Ll[jt][kk]);
      }
    }
    auto GLOAD = [&](int bb){
      #pragma unroll
      for (int i=0;i<2;++i){
        const float* src = xrow + (size_t)bb*16*VV + pv*512 + i*256 + l*4;
        float* dst = &XR[(bb&3)*2048 + pv*512 + i*256];
        gload16f(src, dst);
      }
    };
    auto CONV = [&](int bb){
      if (pt < 256){
        const int buf=bb&1, kk=pt>>6, qq=(pt>>4)&3, s=pt&15;
        const float* src = &XR[(bb&3)*2048 + s*VV + kk*32 + qq*8];
        float tmp[8];
        #pragma unroll
        for (int j=0;j<8;++j) tmp[j] = src[j];
        short8 hi, lo; splitpack(tmp, hi, lo);
        *(short8*)&XAh[XA_IDX(buf,kk,qq,s)] = hi;
        *(short8*)&XAl[XA_IDX(buf,kk,qq,s)] = lo;
      }
    };
    auto PREB = [&](int bb){
      const int buf = bb&1;
      short8 Ah[4], Al[4];
      #pragma unroll
      for (int kk=0;kk<4;++kk){
        Ah[kk] = *(const short8*)&XAh[XA_IDX(buf,kk,(l>>4),(l&15))];
        Al[kk] = *(const short8*)&XAl[XA_IDX(buf,kk,(l>>4),(l&15))];
      }
      #pragma unroll
      for (int ntl=0; ntl<4; ++ntl){
        f32x4 acc = {0.f,0.f,0.f,0.f};
        #pragma unroll
        for (int kk=0;kk<4;++kk){
          acc = __builtin_amdgcn_mfma_f32_16x16x32_bf16(Al[kk], Bh[ntl][kk], acc, 0,0,0);
          acc = __builtin_amdgcn_mfma_f32_16x16x32_bf16(Ah[kk], Bl[ntl][kk], acc, 0,0,0);
          acc = __builtin_amdgcn_mfma_f32_16x16x32_bf16(Ah[kk], Bh[ntl][kk], acc, 0,0,0);
        }
        const int n  = (pv*4+ntl)*16 + (l&15);
        const int s0 = buf*16 + (l>>4)*4;
        #pragma unroll
        for (int r=0;r<4;++r) PRE[(s0+r)*256 + n] = acc[r];
      }
    };
    auto LOGB = [&](int bb){
      const int buf = bb&1;
      short8 Ah[2], Al[2];
      #pragma unroll
      for (int kk=0;kk<2;++kk){
        Ah[kk] = *(const short8*)&HAh[HA_IDX(buf,kk,(l>>4),(l&15))];
        Al[kk] = *(const short8*)&HAl[HA_IDX(buf,kk,(l>>4),(l&15))];
      }
      #pragma unroll
      for (int jt=0; jt<2; ++jt){
        f32x4 acc = {0.f,0.f,0.f,0.f};
        #pragma unroll
        for (int kk=0;kk<2;++kk){
          acc = __builtin_amdgcn_mfma_f32_16x16x32_bf16(Al[kk], Lh[jt][kk], acc, 0,0,0);
          acc = __builtin_amdgcn_mfma_f32_16x16x32_bf16(Ah[kk], Ll[jt][kk], acc, 0,0,0);
          acc = __builtin_amdgcn_mfma_f32_16x16x32_bf16(Ah[kk], Lh[jt][kk], acc, 0,0,0);
        }
        const int j  = (pv*2+jt)*16 + (l&15);
        const int t0 = bb*16 + (l>>4)*4;
        #pragma unroll
        for (int r=0;r<4;++r) orow[(size_t)(t0+r)*VV + j] = acc[r];
      }
    };
    auto RELAY = [&](int hs2){
      if (pt < 8){
        const int kk = pt>>2, qq = pt&3;
        const int buf = (hs2>>4)&1, s = hs2&15;
        const float* src = &HR[(hs2&31)*HH + kk*32 + qq*8];
        float tmp[8];
        #pragma unroll
        for (int j=0;j<8;++j) tmp[j] = src[j];
        short8 hi, lo; splitpack(tmp, hi, lo);
        *(short8*)&HAh[HA_IDX(buf,kk,qq,s)] = hi;
        *(short8*)&HAl[HA_IDX(buf,kk,qq,s)] = lo;
      }
    };
    GLOAD(0); GLOAD(1); GLOAD(2);
    asm volatile("s_waitcnt vmcnt(2)" ::: "memory");
    bar_lds();
    CONV(0); CONV(1);
    bar_lds();
    PREB(0);
    bar_lds();
    #pragma unroll 1
    for (int t=0; t<TT; ++t){
      if (t >= 1) RELAY(t-1);
      const int slot = t&15, blk = t>>4;
      if (slot==0){ if (blk+1 < NBF) PREB(blk+1); }
      else if (slot==1){ if (blk >= 1) LOGB(blk-1); }
      else if (slot==2){ if (blk+3 < NBF) GLOAD(blk+3); }
      else if (slot==3){ if (blk+2 < NBF) asm volatile("s_waitcnt vmcnt(2)" ::: "memory"); }
      else if (slot==4){ if (blk+2 < NBF) CONV(blk+2); }
      bar_lds();
    }
    RELAY(TT-1);
    bar_lds();
    LOGB(NBF-1);
  }
}

__global__ __launch_bounds__(256) void softmax_fb_k(float* __restrict__ out)
{
  const int r = blockIdx.x*4 + (threadIdx.x>>6);
  const int l = threadIdx.x & 63;
  float2* p = (float2*)(out + (size_t)r*VV);
  float2 v = p[l];
  float m = fmaxf(v.x, v.y);
  #pragma unroll
  for (int d=1; d<64; d<<=1) m = fmaxf(m, __shfl_xor(m, d));
  float e0 = __expf(v.x - m), e1 = __expf(v.y - m);
  float s = e0 + e1;
  #pragma unroll
  for (int d=1; d<64; d<<=1) s += __shfl_xor(s, d);
  float rs = frcp(s);
  p[l] = make_float2(e0*rs, e1*rs);
}

// ====================== host ======================
extern "C" void kernel_launch(void* const* d_in, const int* in_sizes, int n_in,
                              void* d_out, int out_size, void* d_ws, size_t ws_size,
                              hipStream_t stream) {
  const float* x     = (const float*)d_in[0];
  const float* W_f   = (const float*)d_in[1];
  const float* b_f   = (const float*)d_in[2];
  const float* W_if  = (const float*)d_in[3];
  const float* b_if  = (const float*)d_in[4];
  const float* W_ic  = (const float*)d_in[5];
  const float* b_ic  = (const float*)d_in[6];
  const float* W_o   = (const float*)d_in[7];
  const float* b_o   = (const float*)d_in[8];
  const float* W_out = (const float*)d_in[9];
  const float* b_out = (const float*)d_in[10];
  float* out = (float*)d_out;

  const size_t PRE_B = (size_t)BB*TT*256*sizeof(float);  // 512 MB
  const size_t H_B   = (size_t)BB*TT*HH*sizeof(float);   // 128 MB
  const size_t need  = PRE_B + H_B + 2*32768*2 + 2*8192*2;

  if (ws_size >= need) {
    char* w = (char*)d_ws;
    float* PRE  = (float*)w;
    float* Hbuf = (float*)(w + PRE_B);
    unsigned short* W4h = (unsigned short*)(w + PRE_B + H_B);
    unsigned short* W4l = W4h + 32768;
    unsigned short* WOh = W4l + 32768;
    unsigned short* WOl = WOh + 8192;
    hipLaunchKernelGGL(conv_w_k, dim3(128), dim3(256), 0, stream,
                       W_f, W_if, W_ic, W_o, W_out, W4h, W4l, WOh, WOl);
    hipLaunchKernelGGL(pre_gemm_k, dim3(BB), dim3(512), 0, stream, x, W4h, W4l, PRE);
    hipLaunchKernelGGL(recur10_k, dim3(BB), dim3(256), 0, stream,
                       W_f, b_f, W_if, b_if, W_ic, b_ic, W_o, b_o, PRE, Hbuf);
    hipLaunchKernelGGL(logit_k, dim3(BB), dim3(512), 0, stream, Hbuf, WOh, WOl, b_out, out);
  } else {
    hipLaunchKernelGGL(fused_fb_k, dim3(BB), dim3(512), 0, stream,
                       x, W_f, b_f, W_if, b_if, W_ic, b_ic, W_o, b_o,
                       W_out, b_out, out);
    hipLaunchKernelGGL(softmax_fb_k, dim3(BB*TT/4), dim3(256), 0, stream, out);
  }
}